// Round 6
// baseline (963.004 us; speedup 1.0000x reference)
//
#include <hip/hip_runtime.h>
#include <math.h>

// ---------------------------------------------------------------------------
// SNN generator. Round 6:
//  - conv1: wave tile M64xN32, 25 K-parts (tl), grid 800 blocks (3.1/CU),
//    exact f32 partials streamed to y1p (no atomics), + reduce kernel.
//  - Workspace 95.9 MB (under the 99.3 MB round-0 precedent):
//      wT    f16 [9][128][25600]   at 0           58,982,400 B
//      spkTb u8  [324][25600]      at 58,982,400   8,294,400 B
//      lin   f32                   at 67,276,800     262,144 B
//      I     f32                   at 67,538,944   1,048,576 B
//      y1    f32                   at 68,587,520   1,048,576 B
//      y1p   f32 [25][8][128][256] at 69,636,096  26,214,400 B
//    phase B (aliases wT after conv1): x2p, y2n, y2 at 0..9,199,616 B
// ---------------------------------------------------------------------------

typedef _Float16 half8 __attribute__((ext_vector_type(8)));
typedef float f32x4 __attribute__((ext_vector_type(4)));
typedef unsigned int uint4v __attribute__((ext_vector_type(4)));

union AFrag { uint4v u4; unsigned int u[4]; half8 h; };

__global__ __launch_bounds__(256) void k_linear(
    const float* __restrict__ z, const float* __restrict__ w,
    const float* __restrict__ bias, float* __restrict__ out) {
  int g = blockIdx.x * 256 + threadIdx.x;   // 65536 = (b, j)
  int b = g >> 13, j = g & 8191;
  float acc = bias[j];
  const float* zp = z + b * 100;
  for (int l = 0; l < 100; ++l) acc += zp[l] * w[l * 8192 + j];
  out[g] = acc;
}

// BN1 (stats over 512, eps 1e-5) + nearest upsample 2x -> I (8,128,16,16)
__global__ __launch_bounds__(256) void k_bn1_up(
    const float* __restrict__ lin, const float* __restrict__ g1,
    const float* __restrict__ be1, float* __restrict__ I) {
  int ch = blockIdx.x, tid = threadIdx.x;
  __shared__ float red[256];
  int n0 = tid, n1 = tid + 256;                       // n = b*64 + hw
  float v0 = lin[(n0 >> 6) * 8192 + ch * 64 + (n0 & 63)];
  float v1 = lin[(n1 >> 6) * 8192 + ch * 64 + (n1 & 63)];
  red[tid] = v0 + v1; __syncthreads();
  for (int s = 128; s > 0; s >>= 1) { if (tid < s) red[tid] += red[tid + s]; __syncthreads(); }
  float mean = red[0] * (1.0f / 512.0f);
  __syncthreads();
  float d0 = v0 - mean, d1 = v1 - mean;
  red[tid] = d0 * d0 + d1 * d1; __syncthreads();
  for (int s = 128; s > 0; s >>= 1) { if (tid < s) red[tid] += red[tid + s]; __syncthreads(); }
  float var = red[0] * (1.0f / 512.0f);
  float coef = g1[ch] / sqrtf(var + 1e-5f);
  float beta = be1[ch];
  float q0 = (v0 - mean) * coef + beta;
  float q1 = (v1 - mean) * coef + beta;
#pragma unroll
  for (int k = 0; k < 2; ++k) {
    int n = k ? n1 : n0; float q = k ? q1 : q0;
    int b = n >> 6, hw = n & 63, h = hw >> 3, w = hw & 7;
    float* o = I + (size_t)(b * 128 + ch) * 256 + (2 * h) * 16 + 2 * w;
    o[0] = q; o[1] = q; o[16] = q; o[17] = q;
  }
}

// LIF with bit-packed transposed spike output.
// spkTb[pos][col/8] bit (col&7), col = t*1024 + plane. Halo pre-zeroed.
__global__ __launch_bounds__(256) void k_lif(
    const float* __restrict__ I, unsigned char* __restrict__ spkTb) {
  int g = blockIdx.x * 256 + threadIdx.x;
  int px = g >> 10, plane = g & 1023;
  int lane = threadIdx.x & 63;
  float in = I[plane * 256 + px];
  int pos = ((px >> 4) + 1) * 18 + (px & 15) + 1;
  unsigned long long* wsrow =
      (unsigned long long*)(spkTb + (size_t)pos * 25600 + ((plane - lane) >> 3));
  float mem = 0.0f;
  for (int t = 0; t < 200; ++t) {
    float reset = (mem > 1.0f) ? 1.0f : 0.0f;
    mem = 0.95f * mem + in - reset;
    unsigned long long m = __ballot(mem > 1.0f);
    if (lane == 0) wsrow[t * 16] = m;   // t*128 bytes
  }
}

// Weight transform, LDS-transposed: w_c1 (128,25600,3,3) fp32 -> wT[tap][oc][c]
__global__ __launch_bounds__(256) void k_wtrans(
    const float* __restrict__ wc1, _Float16* __restrict__ wT) {
  __shared__ float t[2304];
  int oc = blockIdx.x / 100, cg = blockIdx.x % 100;
  int c0 = cg * 256, tid = threadIdx.x;
  const float* src = wc1 + (size_t)oc * 230400 + (size_t)c0 * 9;
#pragma unroll
  for (int i = 0; i < 9; ++i) t[tid + i * 256] = src[tid + i * 256];
  __syncthreads();
#pragma unroll
  for (int tap = 0; tap < 9; ++tap)
    wT[(size_t)(tap * 128 + oc) * 25600 + c0 + tid] = (_Float16)t[tid * 9 + tap];
}

// bit->f16 expand: byte b -> 8 halfs {0,1.0h}, via multiply-spread + v_perm.
__device__ inline void expandp(unsigned int b, AFrag& f) {
  unsigned int lo = ((b & 0xFu) * 0x00204081u) & 0x01010101u;
  unsigned int hi = ((b >> 4) * 0x00204081u) & 0x01010101u;
  lo *= 0x3Cu; hi *= 0x3Cu;
  f.u[0] = __builtin_amdgcn_perm(0u, lo, 0x01040004u);
  f.u[1] = __builtin_amdgcn_perm(0u, lo, 0x03040204u);
  f.u[2] = __builtin_amdgcn_perm(0u, hi, 0x01040004u);
  f.u[3] = __builtin_amdgcn_perm(0u, hi, 0x03040204u);
}

// conv1 implicit GEMM, streaming, no LDS / no atomics.
// grid (x = nq*8 + b, y = tl, z = mhalf); block 256 thr = 4 waves.
// Block tile M64 x N128; wave = M64 x N32 (px [nq*128+wave*32, +32)).
// K = 1024 ch x 9 taps (tl slice); bigstep = 128 ch (s128 0..7).
// MFMA 16x16x32 f16; D col=l16(px), row=quad*4+r (oc).
// Writes f32 partials y1p[((tl*8+b)*128 + oc)*256 + px].
__global__ __launch_bounds__(256, 3) void k_conv1_mfma(
    const unsigned char* __restrict__ spkTb, const _Float16* __restrict__ wT,
    float* __restrict__ y1p) {
  int bx = blockIdx.x;
  int nq = bx >> 3, b = bx & 7;
  int tl = blockIdx.y, mhalf = blockIdx.z;
  int wave = threadIdx.x >> 6, lane = threadIdx.x & 63;
  int quad = lane >> 4, l16 = lane & 15;
  int qs = quad * 8;
  int T = b * 25 + tl;
  int cbase = tl * 1024;
  int pxb = nq * 128 + wave * 32;
  int h0 = pxb >> 4;                       // output row base (2 rows per wave)

  // A: oc = mhalf*64 + mt*16 + l16; ch = cbase + s128*128 + s*32 + quad*8
  const _Float16* a0 = wT + (size_t)(mhalf * 64 + l16) * 25600 + cbase + quad * 8;
  // B: byte = pos*25600 + T*128 + s128*16 (dword s, byte quad)
  const unsigned char* b0 = spkTb + (size_t)T * 128;

  f32x4 acc[4][2] = {};                    // [mt][nt]

  for (int tap = 0; tap < 9; ++tap) {
    int dh = tap / 3, dw = tap - dh * 3;
    const _Float16* atap = a0 + (size_t)tap * (128 * 25600);
    const unsigned char* bt0 = b0 + (size_t)((h0 + dh) * 18 + l16 + dw) * 25600;
    const unsigned char* bt1 = b0 + (size_t)((h0 + 1 + dh) * 18 + l16 + dw) * 25600;
    for (int s128 = 0; s128 < 8; ++s128) {
      AFrag af[4][4];
#pragma unroll
      for (int mt = 0; mt < 4; ++mt)
#pragma unroll
        for (int s = 0; s < 4; ++s)
          af[mt][s].u4 = *(const uint4v*)(atap + (size_t)mt * 16 * 25600 + s128 * 128 + s * 32);
      uint4v bv0 = *(const uint4v*)(bt0 + s128 * 16);
      uint4v bv1 = *(const uint4v*)(bt1 + s128 * 16);
#pragma unroll
      for (int s = 0; s < 4; ++s) {
        AFrag bf0; expandp((bv0[s] >> qs) & 0xFFu, bf0);
        AFrag bf1; expandp((bv1[s] >> qs) & 0xFFu, bf1);
#pragma unroll
        for (int mt = 0; mt < 4; ++mt) {
          acc[mt][0] = __builtin_amdgcn_mfma_f32_16x16x32_f16(
              af[mt][s].h, bf0.h, acc[mt][0], 0, 0, 0);
          acc[mt][1] = __builtin_amdgcn_mfma_f32_16x16x32_f16(
              af[mt][s].h, bf1.h, acc[mt][1], 0, 0, 0);
        }
      }
    }
  }

  float* obase = y1p + (size_t)(tl * 8 + b) * 128 * 256;
#pragma unroll
  for (int mt = 0; mt < 4; ++mt)
#pragma unroll
    for (int nt = 0; nt < 2; ++nt) {
#pragma unroll
      for (int r = 0; r < 4; ++r) {
        int oc = mhalf * 64 + mt * 16 + quad * 4 + r;
        int px = pxb + nt * 16 + l16;
        obase[(size_t)oc * 256 + px] = acc[mt][nt][r];
      }
    }
}

// reduce 25 tl-partials -> y1 (b,oc,16,16)
__global__ __launch_bounds__(256) void k_reduce1(
    const float* __restrict__ y1p, float* __restrict__ y1) {
  int g = blockIdx.x * 256 + threadIdx.x;  // (b, oc, px): b = g>>15
  int b = g >> 15, rest = g & 32767;
  float acc = 0.0f;
  for (int tl = 0; tl < 25; ++tl)
    acc += y1p[(size_t)(tl * 8 + b) * 32768 + rest];
  y1[g] = acc;
}

// BN2 (eps 0.8, stats over 2048) + conv1 bias + leaky(0.2) + upsample2x
__global__ __launch_bounds__(256) void k_bn2_up(
    const float* __restrict__ y1, const float* __restrict__ bc1,
    const float* __restrict__ g2, const float* __restrict__ be2,
    float* __restrict__ x2p) {
  int ch = blockIdx.x, tid = threadIdx.x;
  __shared__ float red[256];
  float bias = bc1[ch];
  float v[8]; float s = 0.0f;
#pragma unroll
  for (int k = 0; k < 8; ++k) {
    int n = tid + k * 256;  // n = b*256 + px
    v[k] = y1[(size_t)((n >> 8) * 128 + ch) * 256 + (n & 255)] + bias;
    s += v[k];
  }
  red[tid] = s; __syncthreads();
  for (int st = 128; st > 0; st >>= 1) { if (tid < st) red[tid] += red[tid + st]; __syncthreads(); }
  float mean = red[0] * (1.0f / 2048.0f);
  __syncthreads();
  s = 0.0f;
#pragma unroll
  for (int k = 0; k < 8; ++k) { float d = v[k] - mean; s += d * d; }
  red[tid] = s; __syncthreads();
  for (int st = 128; st > 0; st >>= 1) { if (tid < st) red[tid] += red[tid + st]; __syncthreads(); }
  float var = red[0] * (1.0f / 2048.0f);
  float coef = g2[ch] / sqrtf(var + 0.8f);
  float beta = be2[ch];
#pragma unroll
  for (int k = 0; k < 8; ++k) {
    int n = tid + k * 256;
    int b = n >> 8, px = n & 255, h = px >> 4, w = px & 15;
    float q = (v[k] - mean) * coef + beta;
    q = (q >= 0.0f) ? q : 0.2f * q;
    float* o = x2p + (size_t)(b * 128 + ch) * 1156 + (2 * h + 1) * 34 + (2 * w + 1);
    o[0] = q; o[1] = q; o[34] = q; o[35] = q;
  }
}

// conv2: block=(octile 0..15, b), thread = 4 pixels x 4 oc
__global__ __launch_bounds__(256) void k_conv2(
    const float* __restrict__ x2p, const float* __restrict__ wc2,
    const float* __restrict__ bc2, float* __restrict__ y2) {
  int octile = blockIdx.x, b = blockIdx.y, tid = threadIdx.x;
  float acc[16];
#pragma unroll
  for (int i = 0; i < 16; ++i) acc[i] = 0.0f;
  const float* base = x2p + (size_t)(b * 128) * 1156;
  for (int ch = 0; ch < 128; ++ch) {
    const float* pl = base + (size_t)ch * 1156;
    float sv[4][9];
#pragma unroll
    for (int j = 0; j < 4; ++j) {
      int p = tid + j * 256, h = p >> 5, w = p & 31;
      const float* pp = pl + h * 34 + w;
      sv[j][0] = pp[0];  sv[j][1] = pp[1];  sv[j][2] = pp[2];
      sv[j][3] = pp[34]; sv[j][4] = pp[35]; sv[j][5] = pp[36];
      sv[j][6] = pp[68]; sv[j][7] = pp[69]; sv[j][8] = pp[70];
    }
#pragma unroll
    for (int ol = 0; ol < 4; ++ol) {
      const float* wp = wc2 + (size_t)((octile * 4 + ol) * 128 + ch) * 9;
#pragma unroll
      for (int j = 0; j < 4; ++j) {
        acc[ol * 4 + j] += sv[j][0] * wp[0] + sv[j][1] * wp[1] + sv[j][2] * wp[2]
                         + sv[j][3] * wp[3] + sv[j][4] * wp[4] + sv[j][5] * wp[5]
                         + sv[j][6] * wp[6] + sv[j][7] * wp[7] + sv[j][8] * wp[8];
      }
    }
  }
#pragma unroll
  for (int ol = 0; ol < 4; ++ol) {
    int oc = octile * 4 + ol;
    float bias = bc2[oc];
#pragma unroll
    for (int j = 0; j < 4; ++j)
      y2[(size_t)(b * 64 + oc) * 1024 + tid + j * 256] = acc[ol * 4 + j] + bias;
  }
}

// BN3 (eps 0.8, stats over 8192) + leaky -> padded y2n
__global__ __launch_bounds__(256) void k_bn3(
    const float* __restrict__ y2, const float* __restrict__ g3,
    const float* __restrict__ be3, float* __restrict__ y2n) {
  int ch = blockIdx.x, tid = threadIdx.x;
  __shared__ float red[256];
  float v[32]; float s = 0.0f;
#pragma unroll
  for (int k = 0; k < 32; ++k) {
    int n = tid + k * 256;  // n = b*1024 + px
    v[k] = y2[(size_t)((n >> 10) * 64 + ch) * 1024 + (n & 1023)];
    s += v[k];
  }
  red[tid] = s; __syncthreads();
  for (int st = 128; st > 0; st >>= 1) { if (tid < st) red[tid] += red[tid + st]; __syncthreads(); }
  float mean = red[0] * (1.0f / 8192.0f);
  __syncthreads();
  s = 0.0f;
#pragma unroll
  for (int k = 0; k < 32; ++k) { float d = v[k] - mean; s += d * d; }
  red[tid] = s; __syncthreads();
  for (int st = 128; st > 0; st >>= 1) { if (tid < st) red[tid] += red[tid + st]; __syncthreads(); }
  float var = red[0] * (1.0f / 8192.0f);
  float coef = g3[ch] / sqrtf(var + 0.8f);
  float beta = be3[ch];
#pragma unroll
  for (int k = 0; k < 32; ++k) {
    int n = tid + k * 256;
    int b = n >> 10, px = n & 1023, h = px >> 5, w = px & 31;
    float q = (v[k] - mean) * coef + beta;
    q = (q >= 0.0f) ? q : 0.2f * q;
    y2n[(size_t)(b * 64 + ch) * 1156 + (h + 1) * 34 + (w + 1)] = q;
  }
}

// conv3 (3 oc) + bias + tanh -> d_out (8,3,32,32)
__global__ __launch_bounds__(256) void k_conv3(
    const float* __restrict__ y2n, const float* __restrict__ wc3,
    const float* __restrict__ bc3, float* __restrict__ out) {
  int quarter = blockIdx.x & 3, b = blockIdx.x >> 2;
  int p = quarter * 256 + threadIdx.x, h = p >> 5, w = p & 31;
  float a0 = 0.0f, a1 = 0.0f, a2 = 0.0f;
  const float* base = y2n + (size_t)(b * 64) * 1156 + h * 34 + w;
  for (int ch = 0; ch < 64; ++ch) {
    const float* pp = base + (size_t)ch * 1156;
    float s0 = pp[0],  s1 = pp[1],  s2 = pp[2];
    float s3 = pp[34], s4 = pp[35], s5 = pp[36];
    float s6 = pp[68], s7 = pp[69], s8 = pp[70];
    const float* w0 = wc3 + (size_t)ch * 9;
    const float* w1 = wc3 + (size_t)(64 + ch) * 9;
    const float* w2 = wc3 + (size_t)(128 + ch) * 9;
    a0 += s0*w0[0]+s1*w0[1]+s2*w0[2]+s3*w0[3]+s4*w0[4]+s5*w0[5]+s6*w0[6]+s7*w0[7]+s8*w0[8];
    a1 += s0*w1[0]+s1*w1[1]+s2*w1[2]+s3*w1[3]+s4*w1[4]+s5*w1[5]+s6*w1[6]+s7*w1[7]+s8*w1[8];
    a2 += s0*w2[0]+s1*w2[1]+s2*w2[2]+s3*w2[3]+s4*w2[4]+s5*w2[5]+s6*w2[6]+s7*w2[7]+s8*w2[8];
  }
  out[(size_t)(b * 3 + 0) * 1024 + p] = tanhf(a0 + bc3[0]);
  out[(size_t)(b * 3 + 1) * 1024 + p] = tanhf(a1 + bc3[1]);
  out[(size_t)(b * 3 + 2) * 1024 + p] = tanhf(a2 + bc3[2]);
}

extern "C" void kernel_launch(void* const* d_in, const int* in_sizes, int n_in,
                              void* d_out, int out_size, void* d_ws, size_t ws_size,
                              hipStream_t stream) {
  const float* z    = (const float*)d_in[0];
  const float* w_l1 = (const float*)d_in[1];
  const float* b_l1 = (const float*)d_in[2];
  const float* g1   = (const float*)d_in[3];
  const float* be1  = (const float*)d_in[4];
  const float* w_c1 = (const float*)d_in[5];
  const float* b_c1 = (const float*)d_in[6];
  const float* g2   = (const float*)d_in[7];
  const float* be2  = (const float*)d_in[8];
  const float* w_c2 = (const float*)d_in[9];
  const float* b_c2 = (const float*)d_in[10];
  const float* g3   = (const float*)d_in[11];
  const float* be3  = (const float*)d_in[12];
  const float* w_c3 = (const float*)d_in[13];
  const float* b_c3 = (const float*)d_in[14];
  float* out = (float*)d_out;

  char* ws = (char*)d_ws;
  // phase A
  _Float16* wT = (_Float16*)ws;                             // 58,982,400 B
  unsigned char* spkTb = (unsigned char*)(ws + 58982400);   //  8,294,400 B
  float* lin = (float*)(ws + 67276800);                     //    262,144 B
  float* I   = (float*)(ws + 67538944);                     //  1,048,576 B
  float* y1  = (float*)(ws + 68587520);                     //  1,048,576 B
  float* y1p = (float*)(ws + 69636096);                     // 26,214,400 B
  // phase B (aliases wT region; written only after conv1 completes)
  float* x2p = (float*)ws;                                  //  4,734,976 B
  float* y2n = (float*)(ws + 4734976);                      //  2,367,488 B
  float* y2  = (float*)(ws + 7102464);                      //  2,097,152 B

  size_t spkTb_bytes = (size_t)324 * 25600;

  hipMemsetAsync(spkTb, 0, spkTb_bytes, stream);

  k_wtrans <<<12800, 256, 0, stream>>>(w_c1, wT);
  k_linear <<<256, 256, 0, stream>>>(z, w_l1, b_l1, lin);
  k_bn1_up <<<128, 256, 0, stream>>>(lin, g1, be1, I);
  k_lif    <<<1024, 256, 0, stream>>>(I, spkTb);
  k_conv1_mfma<<<dim3(16, 25, 2), 256, 0, stream>>>(spkTb, wT, y1p);
  k_reduce1<<<1024, 256, 0, stream>>>(y1p, y1);

  // phase B setup (must be after conv1: x2p/y2n alias the wT region)
  hipMemsetAsync(x2p, 0, (size_t)1183744 * 4, stream);
  hipMemsetAsync(y2n, 0, (size_t)591872 * 4, stream);

  k_bn2_up <<<128, 256, 0, stream>>>(y1, b_c1, g2, be2, x2p);
  k_conv2  <<<dim3(16, 8), 256, 0, stream>>>(x2p, w_c2, b_c2, y2);
  k_bn3    <<<64, 256, 0, stream>>>(y2, g3, be3, y2n);
  k_conv3  <<<32, 256, 0, stream>>>(y2n, w_c3, b_c3, out);
}

// Round 7
// 676.456 us; speedup vs baseline: 1.4236x; 1.4236x over previous
//
#include <hip/hip_runtime.h>
#include <math.h>

// ---------------------------------------------------------------------------
// SNN generator. Round 7: break memory-channel aliasing.
//  - wT row stride 25600 -> 25632 f16 (51,264 B = 801 lines, odd)
//  - spkTb row stride 25600 -> 25664 B (401 lines, odd)
//    (power-of-two-line strides put all 16 lanes of each load on ONE channel;
//     odd-line strides cycle all channels -> this was the 20k-cyc load stall
//     AND the hidden ~300us k_wtrans write serialization)
//  - conv1: block M32xN256 (4 waves x M32xN64), grid (32, 25) = 800 blocks,
//    K = 1024ch x 9 taps; per bigstep 12 loads / 16 expands / 32 MFMAs;
//    f32 partials streamed to y1p (no atomics) + reduce.
//
// Workspace (95.9 MB):
//   wT    f16 [9][128][25632]   at 0           59,056,128 B
//   spkTb u8  [324][25664]      at 59,056,128   8,315,136 B
//   lin   f32                   at 67,371,264     262,144 B
//   I     f32                   at 67,633,408   1,048,576 B
//   y1    f32                   at 68,681,984   1,048,576 B
//   y1p   f32 [25][8][128][256] at 69,730,560  26,214,400 B
//  phase B (aliases wT after conv1): x2p, y2n, y2 at 0..9,199,616 B
// ---------------------------------------------------------------------------

#define WROW 25632      // f16 elems per wT row (801 cache lines)
#define SROW 25664      // bytes per spkTb row (401 cache lines)

typedef _Float16 half8 __attribute__((ext_vector_type(8)));
typedef float f32x4 __attribute__((ext_vector_type(4)));
typedef unsigned int uint4v __attribute__((ext_vector_type(4)));

union AFrag { uint4v u4; unsigned int u[4]; half8 h; };

__global__ __launch_bounds__(256) void k_linear(
    const float* __restrict__ z, const float* __restrict__ w,
    const float* __restrict__ bias, float* __restrict__ out) {
  int g = blockIdx.x * 256 + threadIdx.x;   // 65536 = (b, j)
  int b = g >> 13, j = g & 8191;
  float acc = bias[j];
  const float* zp = z + b * 100;
  for (int l = 0; l < 100; ++l) acc += zp[l] * w[l * 8192 + j];
  out[g] = acc;
}

// BN1 (stats over 512, eps 1e-5) + nearest upsample 2x -> I (8,128,16,16)
__global__ __launch_bounds__(256) void k_bn1_up(
    const float* __restrict__ lin, const float* __restrict__ g1,
    const float* __restrict__ be1, float* __restrict__ I) {
  int ch = blockIdx.x, tid = threadIdx.x;
  __shared__ float red[256];
  int n0 = tid, n1 = tid + 256;                       // n = b*64 + hw
  float v0 = lin[(n0 >> 6) * 8192 + ch * 64 + (n0 & 63)];
  float v1 = lin[(n1 >> 6) * 8192 + ch * 64 + (n1 & 63)];
  red[tid] = v0 + v1; __syncthreads();
  for (int s = 128; s > 0; s >>= 1) { if (tid < s) red[tid] += red[tid + s]; __syncthreads(); }
  float mean = red[0] * (1.0f / 512.0f);
  __syncthreads();
  float d0 = v0 - mean, d1 = v1 - mean;
  red[tid] = d0 * d0 + d1 * d1; __syncthreads();
  for (int s = 128; s > 0; s >>= 1) { if (tid < s) red[tid] += red[tid + s]; __syncthreads(); }
  float var = red[0] * (1.0f / 512.0f);
  float coef = g1[ch] / sqrtf(var + 1e-5f);
  float beta = be1[ch];
  float q0 = (v0 - mean) * coef + beta;
  float q1 = (v1 - mean) * coef + beta;
#pragma unroll
  for (int k = 0; k < 2; ++k) {
    int n = k ? n1 : n0; float q = k ? q1 : q0;
    int b = n >> 6, hw = n & 63, h = hw >> 3, w = hw & 7;
    float* o = I + (size_t)(b * 128 + ch) * 256 + (2 * h) * 16 + 2 * w;
    o[0] = q; o[1] = q; o[16] = q; o[17] = q;
  }
}

// LIF with bit-packed transposed spike output.
// spkTb[pos][col/8] bit (col&7), col = t*1024 + plane. Halo pre-zeroed.
__global__ __launch_bounds__(256) void k_lif(
    const float* __restrict__ I, unsigned char* __restrict__ spkTb) {
  int g = blockIdx.x * 256 + threadIdx.x;
  int px = g >> 10, plane = g & 1023;
  int lane = threadIdx.x & 63;
  float in = I[plane * 256 + px];
  int pos = ((px >> 4) + 1) * 18 + (px & 15) + 1;
  unsigned long long* wsrow =
      (unsigned long long*)(spkTb + (size_t)pos * SROW + ((plane - lane) >> 3));
  float mem = 0.0f;
  for (int t = 0; t < 200; ++t) {
    float reset = (mem > 1.0f) ? 1.0f : 0.0f;
    mem = 0.95f * mem + in - reset;
    unsigned long long m = __ballot(mem > 1.0f);
    if (lane == 0) wsrow[t * 16] = m;   // t*128 bytes
  }
}

// Weight transform, LDS-transposed: w_c1 (128,25600,3,3) fp32 -> wT[tap][oc][c]
__global__ __launch_bounds__(256) void k_wtrans(
    const float* __restrict__ wc1, _Float16* __restrict__ wT) {
  __shared__ float t[2304];
  int oc = blockIdx.x / 100, cg = blockIdx.x % 100;
  int c0 = cg * 256, tid = threadIdx.x;
  const float* src = wc1 + (size_t)oc * 230400 + (size_t)c0 * 9;
#pragma unroll
  for (int i = 0; i < 9; ++i) t[tid + i * 256] = src[tid + i * 256];
  __syncthreads();
#pragma unroll
  for (int tap = 0; tap < 9; ++tap)
    wT[(size_t)(tap * 128 + oc) * WROW + c0 + tid] = (_Float16)t[tid * 9 + tap];
}

// bit->f16 expand: byte b -> 8 halfs {0,1.0h}, via multiply-spread + v_perm.
__device__ inline void expandp(unsigned int b, AFrag& f) {
  unsigned int lo = ((b & 0xFu) * 0x00204081u) & 0x01010101u;
  unsigned int hi = ((b >> 4) * 0x00204081u) & 0x01010101u;
  lo *= 0x3Cu; hi *= 0x3Cu;
  f.u[0] = __builtin_amdgcn_perm(0u, lo, 0x01040004u);
  f.u[1] = __builtin_amdgcn_perm(0u, lo, 0x03040204u);
  f.u[2] = __builtin_amdgcn_perm(0u, hi, 0x01040004u);
  f.u[3] = __builtin_amdgcn_perm(0u, hi, 0x03040204u);
}

// conv1 implicit GEMM, streaming, no LDS / no atomics.
// grid (x = b*4 + mq, y = tl); block 256 = 4 waves.
// Block tile M32 x N256; wave = M32 x N64 (px [wave*64, +64)).
// K = 1024 ch x 9 taps (tl slice); bigstep = 128 ch (s128 0..7).
// MFMA 16x16x32 f16; D col=l16(px), row=quad*4+r (oc).
// Writes f32 partials y1p[((tl*8+b)*128 + oc)*256 + px].
__global__ __launch_bounds__(256, 3) void k_conv1_mfma(
    const unsigned char* __restrict__ spkTb, const _Float16* __restrict__ wT,
    float* __restrict__ y1p) {
  int b = blockIdx.x >> 2, mq = blockIdx.x & 3;
  int tl = blockIdx.y;
  int wave = threadIdx.x >> 6, lane = threadIdx.x & 63;
  int quad = lane >> 4, l16 = lane & 15;
  int qs = quad * 8;
  int T = b * 25 + tl;
  int cbase = tl * 1024;
  int h0 = wave * 4;                       // 4 output rows per wave

  // A: oc = mq*32 + mt*16 + l16; ch = cbase + s128*128 + s*32 + quad*8
  const _Float16* a0 = wT + (size_t)(mq * 32 + l16) * WROW + cbase + quad * 8;
  // B: byte = pos*SROW + T*128 + s128*16 (dword s, byte quad)
  const unsigned char* b0 = spkTb + (size_t)T * 128;

  f32x4 acc[2][4] = {};                    // [mt][nt]

  for (int tap = 0; tap < 9; ++tap) {
    int dh = tap / 3, dw = tap - dh * 3;
    const _Float16* atap = a0 + (size_t)tap * (128 * WROW);
    const unsigned char* btap = b0 + (size_t)((h0 + dh) * 18 + l16 + dw) * SROW;
#pragma unroll 2
    for (int s128 = 0; s128 < 8; ++s128) {
      AFrag af[2][4];
#pragma unroll
      for (int mt = 0; mt < 2; ++mt)
#pragma unroll
        for (int s = 0; s < 4; ++s)
          af[mt][s].u4 = *(const uint4v*)(atap + (size_t)mt * 16 * WROW + s128 * 128 + s * 32);
      uint4v bx[4];
#pragma unroll
      for (int nt = 0; nt < 4; ++nt)
        bx[nt] = *(const uint4v*)(btap + (size_t)nt * 18 * SROW + s128 * 16);
#pragma unroll
      for (int s = 0; s < 4; ++s) {
#pragma unroll
        for (int nt = 0; nt < 4; ++nt) {
          AFrag bf; expandp((bx[nt][s] >> qs) & 0xFFu, bf);
          acc[0][nt] = __builtin_amdgcn_mfma_f32_16x16x32_f16(
              af[0][s].h, bf.h, acc[0][nt], 0, 0, 0);
          acc[1][nt] = __builtin_amdgcn_mfma_f32_16x16x32_f16(
              af[1][s].h, bf.h, acc[1][nt], 0, 0, 0);
        }
      }
    }
  }

  float* obase = y1p + (size_t)(tl * 8 + b) * 128 * 256;
#pragma unroll
  for (int mt = 0; mt < 2; ++mt)
#pragma unroll
    for (int nt = 0; nt < 4; ++nt) {
      int h = h0 + nt;
#pragma unroll
      for (int r = 0; r < 4; ++r) {
        int oc = mq * 32 + mt * 16 + quad * 4 + r;
        obase[(size_t)oc * 256 + h * 16 + l16] = acc[mt][nt][r];
      }
    }
}

// reduce 25 tl-partials -> y1 (b,oc,16,16)
__global__ __launch_bounds__(256) void k_reduce1(
    const float* __restrict__ y1p, float* __restrict__ y1) {
  int g = blockIdx.x * 256 + threadIdx.x;  // (b, oc, px): b = g>>15
  int b = g >> 15, rest = g & 32767;
  float acc = 0.0f;
  for (int tl = 0; tl < 25; ++tl)
    acc += y1p[(size_t)(tl * 8 + b) * 32768 + rest];
  y1[g] = acc;
}

// BN2 (eps 0.8, stats over 2048) + conv1 bias + leaky(0.2) + upsample2x
__global__ __launch_bounds__(256) void k_bn2_up(
    const float* __restrict__ y1, const float* __restrict__ bc1,
    const float* __restrict__ g2, const float* __restrict__ be2,
    float* __restrict__ x2p) {
  int ch = blockIdx.x, tid = threadIdx.x;
  __shared__ float red[256];
  float bias = bc1[ch];
  float v[8]; float s = 0.0f;
#pragma unroll
  for (int k = 0; k < 8; ++k) {
    int n = tid + k * 256;  // n = b*256 + px
    v[k] = y1[(size_t)((n >> 8) * 128 + ch) * 256 + (n & 255)] + bias;
    s += v[k];
  }
  red[tid] = s; __syncthreads();
  for (int st = 128; st > 0; st >>= 1) { if (tid < st) red[tid] += red[tid + st]; __syncthreads(); }
  float mean = red[0] * (1.0f / 2048.0f);
  __syncthreads();
  s = 0.0f;
#pragma unroll
  for (int k = 0; k < 8; ++k) { float d = v[k] - mean; s += d * d; }
  red[tid] = s; __syncthreads();
  for (int st = 128; st > 0; st >>= 1) { if (tid < st) red[tid] += red[tid + st]; __syncthreads(); }
  float var = red[0] * (1.0f / 2048.0f);
  float coef = g2[ch] / sqrtf(var + 0.8f);
  float beta = be2[ch];
#pragma unroll
  for (int k = 0; k < 8; ++k) {
    int n = tid + k * 256;
    int b = n >> 8, px = n & 255, h = px >> 4, w = px & 15;
    float q = (v[k] - mean) * coef + beta;
    q = (q >= 0.0f) ? q : 0.2f * q;
    float* o = x2p + (size_t)(b * 128 + ch) * 1156 + (2 * h + 1) * 34 + (2 * w + 1);
    o[0] = q; o[1] = q; o[34] = q; o[35] = q;
  }
}

// conv2: block=(octile 0..15, b), thread = 4 pixels x 4 oc
__global__ __launch_bounds__(256) void k_conv2(
    const float* __restrict__ x2p, const float* __restrict__ wc2,
    const float* __restrict__ bc2, float* __restrict__ y2) {
  int octile = blockIdx.x, b = blockIdx.y, tid = threadIdx.x;
  float acc[16];
#pragma unroll
  for (int i = 0; i < 16; ++i) acc[i] = 0.0f;
  const float* base = x2p + (size_t)(b * 128) * 1156;
  for (int ch = 0; ch < 128; ++ch) {
    const float* pl = base + (size_t)ch * 1156;
    float sv[4][9];
#pragma unroll
    for (int j = 0; j < 4; ++j) {
      int p = tid + j * 256, h = p >> 5, w = p & 31;
      const float* pp = pl + h * 34 + w;
      sv[j][0] = pp[0];  sv[j][1] = pp[1];  sv[j][2] = pp[2];
      sv[j][3] = pp[34]; sv[j][4] = pp[35]; sv[j][5] = pp[36];
      sv[j][6] = pp[68]; sv[j][7] = pp[69]; sv[j][8] = pp[70];
    }
#pragma unroll
    for (int ol = 0; ol < 4; ++ol) {
      const float* wp = wc2 + (size_t)((octile * 4 + ol) * 128 + ch) * 9;
#pragma unroll
      for (int j = 0; j < 4; ++j) {
        acc[ol * 4 + j] += sv[j][0] * wp[0] + sv[j][1] * wp[1] + sv[j][2] * wp[2]
                         + sv[j][3] * wp[3] + sv[j][4] * wp[4] + sv[j][5] * wp[5]
                         + sv[j][6] * wp[6] + sv[j][7] * wp[7] + sv[j][8] * wp[8];
      }
    }
  }
#pragma unroll
  for (int ol = 0; ol < 4; ++ol) {
    int oc = octile * 4 + ol;
    float bias = bc2[oc];
#pragma unroll
    for (int j = 0; j < 4; ++j)
      y2[(size_t)(b * 64 + oc) * 1024 + tid + j * 256] = acc[ol * 4 + j] + bias;
  }
}

// BN3 (eps 0.8, stats over 8192) + leaky -> padded y2n
__global__ __launch_bounds__(256) void k_bn3(
    const float* __restrict__ y2, const float* __restrict__ g3,
    const float* __restrict__ be3, float* __restrict__ y2n) {
  int ch = blockIdx.x, tid = threadIdx.x;
  __shared__ float red[256];
  float v[32]; float s = 0.0f;
#pragma unroll
  for (int k = 0; k < 32; ++k) {
    int n = tid + k * 256;  // n = b*1024 + px
    v[k] = y2[(size_t)((n >> 10) * 64 + ch) * 1024 + (n & 1023)];
    s += v[k];
  }
  red[tid] = s; __syncthreads();
  for (int st = 128; st > 0; st >>= 1) { if (tid < st) red[tid] += red[tid + st]; __syncthreads(); }
  float mean = red[0] * (1.0f / 8192.0f);
  __syncthreads();
  s = 0.0f;
#pragma unroll
  for (int k = 0; k < 32; ++k) { float d = v[k] - mean; s += d * d; }
  red[tid] = s; __syncthreads();
  for (int st = 128; st > 0; st >>= 1) { if (tid < st) red[tid] += red[tid + st]; __syncthreads(); }
  float var = red[0] * (1.0f / 8192.0f);
  float coef = g3[ch] / sqrtf(var + 0.8f);
  float beta = be3[ch];
#pragma unroll
  for (int k = 0; k < 32; ++k) {
    int n = tid + k * 256;
    int b = n >> 10, px = n & 1023, h = px >> 5, w = px & 31;
    float q = (v[k] - mean) * coef + beta;
    q = (q >= 0.0f) ? q : 0.2f * q;
    y2n[(size_t)(b * 64 + ch) * 1156 + (h + 1) * 34 + (w + 1)] = q;
  }
}

// conv3 (3 oc) + bias + tanh -> d_out (8,3,32,32)
__global__ __launch_bounds__(256) void k_conv3(
    const float* __restrict__ y2n, const float* __restrict__ wc3,
    const float* __restrict__ bc3, float* __restrict__ out) {
  int quarter = blockIdx.x & 3, b = blockIdx.x >> 2;
  int p = quarter * 256 + threadIdx.x, h = p >> 5, w = p & 31;
  float a0 = 0.0f, a1 = 0.0f, a2 = 0.0f;
  const float* base = y2n + (size_t)(b * 64) * 1156 + h * 34 + w;
  for (int ch = 0; ch < 64; ++ch) {
    const float* pp = base + (size_t)ch * 1156;
    float s0 = pp[0],  s1 = pp[1],  s2 = pp[2];
    float s3 = pp[34], s4 = pp[35], s5 = pp[36];
    float s6 = pp[68], s7 = pp[69], s8 = pp[70];
    const float* w0 = wc3 + (size_t)ch * 9;
    const float* w1 = wc3 + (size_t)(64 + ch) * 9;
    const float* w2 = wc3 + (size_t)(128 + ch) * 9;
    a0 += s0*w0[0]+s1*w0[1]+s2*w0[2]+s3*w0[3]+s4*w0[4]+s5*w0[5]+s6*w0[6]+s7*w0[7]+s8*w0[8];
    a1 += s0*w1[0]+s1*w1[1]+s2*w1[2]+s3*w1[3]+s4*w1[4]+s5*w1[5]+s6*w1[6]+s7*w1[7]+s8*w1[8];
    a2 += s0*w2[0]+s1*w2[1]+s2*w2[2]+s3*w2[3]+s4*w2[4]+s5*w2[5]+s6*w2[6]+s7*w2[7]+s8*w2[8];
  }
  out[(size_t)(b * 3 + 0) * 1024 + p] = tanhf(a0 + bc3[0]);
  out[(size_t)(b * 3 + 1) * 1024 + p] = tanhf(a1 + bc3[1]);
  out[(size_t)(b * 3 + 2) * 1024 + p] = tanhf(a2 + bc3[2]);
}

extern "C" void kernel_launch(void* const* d_in, const int* in_sizes, int n_in,
                              void* d_out, int out_size, void* d_ws, size_t ws_size,
                              hipStream_t stream) {
  const float* z    = (const float*)d_in[0];
  const float* w_l1 = (const float*)d_in[1];
  const float* b_l1 = (const float*)d_in[2];
  const float* g1   = (const float*)d_in[3];
  const float* be1  = (const float*)d_in[4];
  const float* w_c1 = (const float*)d_in[5];
  const float* b_c1 = (const float*)d_in[6];
  const float* g2   = (const float*)d_in[7];
  const float* be2  = (const float*)d_in[8];
  const float* w_c2 = (const float*)d_in[9];
  const float* b_c2 = (const float*)d_in[10];
  const float* g3   = (const float*)d_in[11];
  const float* be3  = (const float*)d_in[12];
  const float* w_c3 = (const float*)d_in[13];
  const float* b_c3 = (const float*)d_in[14];
  float* out = (float*)d_out;

  char* ws = (char*)d_ws;
  // phase A
  _Float16* wT = (_Float16*)ws;                             // 59,056,128 B
  unsigned char* spkTb = (unsigned char*)(ws + 59056128);   //  8,315,136 B
  float* lin = (float*)(ws + 67371264);                     //    262,144 B
  float* I   = (float*)(ws + 67633408);                     //  1,048,576 B
  float* y1  = (float*)(ws + 68681984);                     //  1,048,576 B
  float* y1p = (float*)(ws + 69730560);                     // 26,214,400 B
  // phase B (aliases wT region; written only after conv1 completes)
  float* x2p = (float*)ws;                                  //  4,734,976 B
  float* y2n = (float*)(ws + 4734976);                      //  2,367,488 B
  float* y2  = (float*)(ws + 7102464);                      //  2,097,152 B

  size_t spkTb_bytes = (size_t)324 * SROW;

  hipMemsetAsync(spkTb, 0, spkTb_bytes, stream);

  k_wtrans <<<12800, 256, 0, stream>>>(w_c1, wT);
  k_linear <<<256, 256, 0, stream>>>(z, w_l1, b_l1, lin);
  k_bn1_up <<<128, 256, 0, stream>>>(lin, g1, be1, I);
  k_lif    <<<1024, 256, 0, stream>>>(I, spkTb);
  k_conv1_mfma<<<dim3(32, 25), 256, 0, stream>>>(spkTb, wT, y1p);
  k_reduce1<<<1024, 256, 0, stream>>>(y1p, y1);

  // phase B setup (must be after conv1: x2p/y2n alias the wT region)
  hipMemsetAsync(x2p, 0, (size_t)1183744 * 4, stream);
  hipMemsetAsync(y2n, 0, (size_t)591872 * 4, stream);

  k_bn2_up <<<128, 256, 0, stream>>>(y1, b_c1, g2, be2, x2p);
  k_conv2  <<<dim3(16, 8), 256, 0, stream>>>(x2p, w_c2, b_c2, y2);
  k_bn3    <<<64, 256, 0, stream>>>(y2, g3, be3, y2n);
  k_conv3  <<<32, 256, 0, stream>>>(y2n, w_c3, b_c3, out);
}